// Round 8
// baseline (202.937 us; speedup 1.0000x reference)
//
#include <hip/hip_runtime.h>
#include <cmath>

#define IH 128
#define IW 128
#define NB 8

typedef __attribute__((ext_vector_type(8))) short bf16x8;
typedef __attribute__((ext_vector_type(4))) float f32x4;

union U4B8 { uint4 u; bf16x8 h; };

// ws layout (float slots):
//   offm  : [NB][27][IH][IW] f32      = 3538944
//   xT    : [NB][IH][IW][64] bf16     = 4194304 float slots
//   wt_dc : [9][64][64] bf16 (k,o,c)  = 18432 float slots
//   wt_om : [9][32][64] bf16 (k,o,c)  = 9216  float slots
#define OFFM_OFF 0
#define XT_OFF   3538944
#define WTDC_OFF (3538944 + 4194304)
#define WTOM_OFF (3538944 + 4194304 + 18432)

// fp32 -> bf16 bits, round-to-nearest-even
__device__ __forceinline__ unsigned short f32_to_bf16(float f) {
    unsigned int u = __float_as_uint(f);
    u += 0x7fffu + ((u >> 16) & 1u);
    return (unsigned short)(u >> 16);
}

// ---------------------------------------------------------------------------
// Kernel 0: weights -> bf16, layout [k][o][c]
// ---------------------------------------------------------------------------
__global__ void transpose_weights(const float* __restrict__ w_dc,
                                  const float* __restrict__ w_om,
                                  unsigned short* __restrict__ wt_dc16,
                                  unsigned short* __restrict__ wt_om16) {
    int idx = blockIdx.x * blockDim.x + threadIdx.x;
    if (idx < 9 * 64 * 64) {
        int k = idx >> 12;
        int o = (idx >> 6) & 63;
        int c = idx & 63;
        wt_dc16[idx] = f32_to_bf16(w_dc[(o * 64 + c) * 9 + k]);
    }
    if (idx < 9 * 32 * 64) {
        int k = idx >> 11;
        int o = (idx >> 6) & 31;
        int c = idx & 63;
        wt_om16[idx] = (o < 27) ? f32_to_bf16(w_om[(o * 64 + c) * 9 + k])
                                : (unsigned short)0;
    }
}

// ---------------------------------------------------------------------------
// Kernel 0b: x NCHW fp32 -> NHWC bf16 (xT[b][y][x][c])
// ---------------------------------------------------------------------------
__global__ __launch_bounds__(256) void transpose_x(
        const float* __restrict__ x, unsigned short* __restrict__ xT) {
    __shared__ float t[64 * 65];
    const int tid = threadIdx.x;
    const int blk = blockIdx.x;
    const int b = blk >> 8;
    const int rem = blk & 255;
    const int h = rem >> 1;
    const int w0 = (rem & 1) << 6;

    for (int i = tid; i < 4096; i += 256) {
        const int c = i >> 6;
        const int w = i & 63;
        t[w * 65 + c] = x[(((size_t)(b * 64 + c)) << 14) + (h << 7) + w0 + w];
    }
    __syncthreads();
    const int c2 = (tid & 31) * 2;
    ushort2* dst = (ushort2*)(xT + (((size_t)b << 20)) + ((size_t)((h << 7) + w0)) * 64 + c2);
#pragma unroll
    for (int p = 0; p < 8; ++p) {
        const int w = (tid >> 5) + p * 8;
        ushort2 u;
        u.x = f32_to_bf16(t[w * 65 + c2]);
        u.y = f32_to_bf16(t[w * 65 + c2 + 1]);
        dst[(size_t)w * 32] = u;
    }
}

// ---------------------------------------------------------------------------
// Kernel 1: conv3x3 -> offset/mask. ALL weights staged once in LDS
// ([k][part][o][8ch], conflict-free); ONE barrier total; A direct from
// global (predicated, coalesced). Wave = 16px x 32o.
// ---------------------------------------------------------------------------
__global__ __launch_bounds__(256, 4) void conv_om_mfma(
        const unsigned short* __restrict__ xT,
        const float* __restrict__ b_om,
        const unsigned short* __restrict__ wt_om16,  // [9][32][64]
        float* __restrict__ offm) {
    __shared__ __align__(16) unsigned short wall[9 * 8 * 32 * 8];  // 36864 B

    const int tid = threadIdx.x;
    // stage all 9 weight slices: 2304 uint4 (9/thread)
    for (int s = tid; s < 2304; s += 256) {
        const int k = s >> 8;
        const int r = s & 255;
        const int p = r >> 5;
        const int o = r & 31;
        ((uint4*)wall)[s] = ((const uint4*)wt_om16)[(k << 8) + (o << 3) + p];
    }
    __syncthreads();

    const int t = (blockIdx.x << 2) + (tid >> 6);   // 16-px tile id
    const int b = t >> 10;
    const int rem = t & 1023;
    const int h = rem >> 3;
    const int w0 = (rem & 7) << 4;
    const int lane = tid & 63;
    const int ln15 = lane & 15;
    const int quad = lane >> 4;

    const unsigned short* xb = xT + ((size_t)b << 20);

    f32x4 acc[2] = {{0.f, 0.f, 0.f, 0.f}, {0.f, 0.f, 0.f, 0.f}};

#pragma unroll
    for (int k = 0; k < 9; ++k) {
        const int kh = k / 3;
        const int kw = k - kh * 3;
        const int y = h + kh - 1;
        const int xx = w0 + ln15 + kw - 1;
        U4B8 a0, a1;
        a0.u = make_uint4(0u, 0u, 0u, 0u);
        a1.u = make_uint4(0u, 0u, 0u, 0u);
        if (y >= 0 && y < IH && xx >= 0 && xx < IW) {
            const unsigned short* p = xb + (((size_t)((y << 7) + xx)) << 6) + (quad << 3);
            a0.u = *(const uint4*)p;
            a1.u = *(const uint4*)(p + 32);
        }
        const unsigned short* wb  = wall + (((k << 3) + quad) << 8);        // part=quad, *32o*8
        const unsigned short* wb4 = wall + (((k << 3) + quad + 4) << 8);    // part=quad+4
#pragma unroll
        for (int ot = 0; ot < 2; ++ot) {
            U4B8 b0, b1;
            b0.u = *(const uint4*)&wb [((ot << 4) + ln15) << 3];
            b1.u = *(const uint4*)&wb4[((ot << 4) + ln15) << 3];
            acc[ot] = __builtin_amdgcn_mfma_f32_16x16x32_bf16(a0.h, b0.h, acc[ot], 0, 0, 0);
            acc[ot] = __builtin_amdgcn_mfma_f32_16x16x32_bf16(a1.h, b1.h, acc[ot], 0, 0, 0);
        }
    }

    // C/D layout: col(o)=lane&15, row(px)=quad*4+reg
#pragma unroll
    for (int ot = 0; ot < 2; ++ot) {
        const int o = (ot << 4) + ln15;
        if (o >= 27) continue;
        const float bias = b_om[o];
        float4 r;
        r.x = acc[ot][0] + bias;
        r.y = acc[ot][1] + bias;
        r.z = acc[ot][2] + bias;
        r.w = acc[ot][3] + bias;
        if (o >= 18) {
            r.x = 2.0f / (1.0f + __expf(-r.x));
            r.y = 2.0f / (1.0f + __expf(-r.y));
            r.z = 2.0f / (1.0f + __expf(-r.z));
            r.w = 2.0f / (1.0f + __expf(-r.w));
        }
        *(float4*)&offm[(((size_t)(b * 27 + o)) << 14) + (h << 7) + w0 + (quad << 2)] = r;
    }
}

// ---------------------------------------------------------------------------
// bilinear corner: accumulate 8+8 channels (frag0 at p, frag1 at p+32)
// ---------------------------------------------------------------------------
__device__ __forceinline__ void corner2(const unsigned short* __restrict__ p,
                                        float wgt, float* v) {
    const uint4 a = *(const uint4*)p;
    const uint4 c = *(const uint4*)(p + 32);
    unsigned int u[8] = {a.x, a.y, a.z, a.w, c.x, c.y, c.z, c.w};
#pragma unroll
    for (int i = 0; i < 8; ++i) {
        v[2 * i]     += wgt * __uint_as_float(u[i] << 16);
        v[2 * i + 1] += wgt * __uint_as_float(u[i] & 0xffff0000u);
    }
}

// ---------------------------------------------------------------------------
// Kernel 2: deformable conv. ALL 9 weight slices staged once in LDS
// ([k][part][o][8ch], 73728 B, conflict-free); ONE barrier total; offsets
// read per-lane from global; gather straight into register A-fragments.
// Wave = 16px x 64o, fully unrolled k-loop, no syncs inside.
// ---------------------------------------------------------------------------
__global__ __launch_bounds__(256, 2) void deform_mfma(
        const unsigned short* __restrict__ xT,
        const float* __restrict__ b_dc,
        const float* __restrict__ offm,              // [B][27][H][W]
        const unsigned short* __restrict__ wt_dc16,  // [9][64][64] (k,o,c)
        float* __restrict__ out) {
    __shared__ __align__(16) unsigned short wall[9 * 8 * 64 * 8];  // 73728 B

    const int tid = threadIdx.x;
    // stage all 9 weight slices: 4608 uint4 (18/thread)
    for (int s = tid; s < 4608; s += 256) {
        const int k = s >> 9;
        const int r = s & 511;
        const int p = r >> 6;
        const int o = r & 63;
        ((uint4*)wall)[s] = ((const uint4*)wt_dc16)[(k << 9) + (o << 3) + p];
    }
    __syncthreads();

    const int t = (blockIdx.x << 2) + (tid >> 6);   // 16-px tile id
    const int b = t >> 10;
    const int rem = t & 1023;
    const int h = rem >> 3;
    const int w0 = (rem & 7) << 4;
    const int lane = tid & 63;
    const int ln15 = lane & 15;
    const int quad = lane >> 4;

    const unsigned short* xb = xT + ((size_t)b << 20);
    const float* ofb = offm + (((size_t)(b * 27)) << 14) + (h << 7) + w0 + ln15;

    f32x4 acc[4];
#pragma unroll
    for (int i = 0; i < 4; ++i) acc[i] = (f32x4){0.f, 0.f, 0.f, 0.f};

#pragma unroll
    for (int k = 0; k < 9; ++k) {
        const float offy = ofb[((size_t)(2 * k)) << 14];
        const float offx = ofb[((size_t)(2 * k + 1)) << 14];
        const float msk  = ofb[((size_t)(18 + k)) << 14];
        const int kh = k / 3;
        const int kw = k - kh * 3;
        const float py  = (float)(h + kh - 1) + offy;
        const float pxf = (float)(w0 + ln15 + kw - 1) + offx;
        const float y0f = floorf(py);
        const float x0f = floorf(pxf);
        const float fy = py - y0f;
        const float fx = pxf - x0f;
        const float wy0 = 1.0f - fy, wx0 = 1.0f - fx;
        const float vy0 = (y0f >= 0.0f && y0f <= 127.0f) ? 1.0f : 0.0f;
        const float vy1 = (y0f >= -1.0f && y0f <= 126.0f) ? 1.0f : 0.0f;
        const float vx0 = (x0f >= 0.0f && x0f <= 127.0f) ? 1.0f : 0.0f;
        const float vx1 = (x0f >= -1.0f && x0f <= 126.0f) ? 1.0f : 0.0f;
        const float w00 = wy0 * wx0 * vy0 * vx0;
        const float w01 = wy0 * fx  * vy0 * vx1;
        const float w10 = fy  * wx0 * vy1 * vx0;
        const float w11 = fy  * fx  * vy1 * vx1;
        const int y0i = min(max((int)y0f, 0), 127);
        const int y1i = min(max((int)y0f + 1, 0), 127);
        const int x0i = min(max((int)x0f, 0), 127);
        const int x1i = min(max((int)x0f + 1, 0), 127);

        float v[16];
#pragma unroll
        for (int i = 0; i < 16; ++i) v[i] = 0.0f;
        const int cofs = quad << 3;
        corner2(xb + ((((size_t)((y0i << 7) + x0i)) << 6) + cofs), w00, v);
        corner2(xb + ((((size_t)((y0i << 7) + x1i)) << 6) + cofs), w01, v);
        corner2(xb + ((((size_t)((y1i << 7) + x0i)) << 6) + cofs), w10, v);
        corner2(xb + ((((size_t)((y1i << 7) + x1i)) << 6) + cofs), w11, v);

        U4B8 a0, a1;
        unsigned int pk[8];
#pragma unroll
        for (int i = 0; i < 8; ++i) {
            const unsigned int lo = f32_to_bf16(v[2 * i] * msk);
            const unsigned int hi = f32_to_bf16(v[2 * i + 1] * msk);
            pk[i] = lo | (hi << 16);
        }
        a0.u = make_uint4(pk[0], pk[1], pk[2], pk[3]);
        a1.u = make_uint4(pk[4], pk[5], pk[6], pk[7]);

        const unsigned short* wb  = wall + (((k << 3) + quad) << 9);       // part=quad, *64o*8
        const unsigned short* wb4 = wall + (((k << 3) + quad + 4) << 9);   // part=quad+4
#pragma unroll
        for (int ot = 0; ot < 4; ++ot) {
            U4B8 b0, b1;
            b0.u = *(const uint4*)&wb [((ot << 4) + ln15) << 3];
            b1.u = *(const uint4*)&wb4[((ot << 4) + ln15) << 3];
            acc[ot] = __builtin_amdgcn_mfma_f32_16x16x32_bf16(a0.h, b0.h, acc[ot], 0, 0, 0);
            acc[ot] = __builtin_amdgcn_mfma_f32_16x16x32_bf16(a1.h, b1.h, acc[ot], 0, 0, 0);
        }
    }

    // epilogue: col(o)=lane&15, row(px)=quad*4+reg
#pragma unroll
    for (int ot = 0; ot < 4; ++ot) {
        const int o = (ot << 4) + ln15;
        const float bias = b_dc[o];
        float4 r;
        r.x = acc[ot][0] + bias;
        r.y = acc[ot][1] + bias;
        r.z = acc[ot][2] + bias;
        r.w = acc[ot][3] + bias;
        *(float4*)&out[(((size_t)(b * 64 + o)) << 14) + (h << 7) + w0 + (quad << 2)] = r;
    }
}

extern "C" void kernel_launch(void* const* d_in, const int* in_sizes, int n_in,
                              void* d_out, int out_size, void* d_ws, size_t ws_size,
                              hipStream_t stream) {
    const float* x    = (const float*)d_in[0];
    const float* w_om = (const float*)d_in[1];
    const float* b_om = (const float*)d_in[2];
    const float* w_dc = (const float*)d_in[3];
    const float* b_dc = (const float*)d_in[4];
    float* out = (float*)d_out;
    float* ws  = (float*)d_ws;

    float* offm = ws + OFFM_OFF;
    unsigned short* xT      = (unsigned short*)(ws + XT_OFF);
    unsigned short* wt_dc16 = (unsigned short*)(ws + WTDC_OFF);
    unsigned short* wt_om16 = (unsigned short*)(ws + WTOM_OFF);

    // 16-px tiles: NB*IH*(IW/16) = 8192 total, 4 waves per block -> 2048 blocks
    const int n_blocks = NB * IH * (IW / 16) / 4;

    transpose_weights<<<144, 256, 0, stream>>>(w_dc, w_om, wt_dc16, wt_om16);
    transpose_x<<<NB * IH * 2, 256, 0, stream>>>(x, xT);
    conv_om_mfma<<<n_blocks, 256, 0, stream>>>(xT, b_om, wt_om16, offm);
    deform_mfma<<<n_blocks, 256, 0, stream>>>(xT, b_dc, offm, wt_dc16, out);
}

// Round 9
// 200.462 us; speedup vs baseline: 1.0123x; 1.0123x over previous
//
#include <hip/hip_runtime.h>
#include <cmath>

#define IH 128
#define IW 128
#define NB 8

typedef __attribute__((ext_vector_type(8))) short bf16x8;
typedef __attribute__((ext_vector_type(4))) float f32x4;

union U4B8 { uint4 u; bf16x8 h; };

// ws layout (float slots):
//   xT    : [NB][IH][IW][64] bf16     = 4194304 float slots
//   wt_dc : [9][64][64] bf16 (k,o,c)  = 18432 float slots
//   wt_om : [9][32][64] bf16 (k,o,c)  = 9216  float slots
#define XT_OFF   0
#define WTDC_OFF 4194304
#define WTOM_OFF (4194304 + 18432)

// fp32 -> bf16 bits, round-to-nearest-even
__device__ __forceinline__ unsigned short f32_to_bf16(float f) {
    unsigned int u = __float_as_uint(f);
    u += 0x7fffu + ((u >> 16) & 1u);
    return (unsigned short)(u >> 16);
}

// ---------------------------------------------------------------------------
// Kernel 0: weights -> bf16, layout [k][o][c]
// ---------------------------------------------------------------------------
__global__ void transpose_weights(const float* __restrict__ w_dc,
                                  const float* __restrict__ w_om,
                                  unsigned short* __restrict__ wt_dc16,
                                  unsigned short* __restrict__ wt_om16) {
    int idx = blockIdx.x * blockDim.x + threadIdx.x;
    if (idx < 9 * 64 * 64) {
        int k = idx >> 12;
        int o = (idx >> 6) & 63;
        int c = idx & 63;
        wt_dc16[idx] = f32_to_bf16(w_dc[(o * 64 + c) * 9 + k]);
    }
    if (idx < 9 * 32 * 64) {
        int k = idx >> 11;
        int o = (idx >> 6) & 31;
        int c = idx & 63;
        wt_om16[idx] = (o < 27) ? f32_to_bf16(w_om[(o * 64 + c) * 9 + k])
                                : (unsigned short)0;
    }
}

// ---------------------------------------------------------------------------
// Kernel 0b: x NCHW fp32 -> NHWC bf16 (xT[b][y][x][c])
// ---------------------------------------------------------------------------
__global__ __launch_bounds__(256) void transpose_x(
        const float* __restrict__ x, unsigned short* __restrict__ xT) {
    __shared__ float t[64 * 65];
    const int tid = threadIdx.x;
    const int blk = blockIdx.x;
    const int b = blk >> 8;
    const int rem = blk & 255;
    const int h = rem >> 1;
    const int w0 = (rem & 1) << 6;

    for (int i = tid; i < 4096; i += 256) {
        const int c = i >> 6;
        const int w = i & 63;
        t[w * 65 + c] = x[(((size_t)(b * 64 + c)) << 14) + (h << 7) + w0 + w];
    }
    __syncthreads();
    const int c2 = (tid & 31) * 2;
    ushort2* dst = (ushort2*)(xT + (((size_t)b << 20)) + ((size_t)((h << 7) + w0)) * 64 + c2);
#pragma unroll
    for (int p = 0; p < 8; ++p) {
        const int w = (tid >> 5) + p * 8;
        ushort2 u;
        u.x = f32_to_bf16(t[w * 65 + c2]);
        u.y = f32_to_bf16(t[w * 65 + c2 + 1]);
        dst[(size_t)w * 32] = u;
    }
}

// ---------------------------------------------------------------------------
// bilinear corner: accumulate 8+8 channels (frag0 at p, frag1 at p+32)
// ---------------------------------------------------------------------------
__device__ __forceinline__ void corner2(const unsigned short* __restrict__ p,
                                        float wgt, float* v) {
    const uint4 a = *(const uint4*)p;
    const uint4 c = *(const uint4*)(p + 32);
    unsigned int u[8] = {a.x, a.y, a.z, a.w, c.x, c.y, c.z, c.w};
#pragma unroll
    for (int i = 0; i < 8; ++i) {
        v[2 * i]     += wgt * __uint_as_float(u[i] << 16);
        v[2 * i + 1] += wgt * __uint_as_float(u[i] & 0xffff0000u);
    }
}

// ---------------------------------------------------------------------------
// FUSED kernel: conv3x3->offset/mask (MFMA) -> LDS -> deformable conv (MFMA).
// Block = 64-px strip (b, h, w0 in {0,64}), 4 waves of 16px each.
// Phase 1: om weights in LDS wall (36 KB), conv, offsets+2*sigmoid(mask)
//          written to offs[27][68] LDS.
// Phase 2: dc weights in same wall (72 KB), barrier-free 9-tap gather+MFMA.
// 3 barriers total. No offm global round-trip.
// ---------------------------------------------------------------------------
__global__ __launch_bounds__(256, 2) void fused_dcn(
        const unsigned short* __restrict__ xT,
        const float* __restrict__ b_om,
        const unsigned short* __restrict__ wt_om16,  // [9][32][64]
        const float* __restrict__ b_dc,
        const unsigned short* __restrict__ wt_dc16,  // [9][64][64]
        float* __restrict__ out) {
    __shared__ __align__(16) unsigned short wall[9 * 8 * 64 * 8];  // 73728 B
    __shared__ __align__(16) float offs[27 * 68];                  // 7344 B

    const int tid = threadIdx.x;
    const int b = blockIdx.x >> 8;
    const int rem = blockIdx.x & 255;
    const int h = rem >> 1;
    const int w0 = (rem & 1) << 6;
    const int wid = tid >> 6;
    const int lane = tid & 63;
    const int ln15 = lane & 15;
    const int quad = lane >> 4;

    const unsigned short* xb = xT + ((size_t)b << 20);

    // ---------------- phase 1: offset/mask conv ----------------
    // stage om wall: 2304 uint4, layout [(k*8+p)*32 + o]
    for (int s = tid; s < 2304; s += 256) {
        const int k = s >> 8;
        const int r = s & 255;
        const int p = r >> 5;
        const int o = r & 31;
        ((uint4*)wall)[s] = ((const uint4*)wt_om16)[(k << 8) + (o << 3) + p];
    }
    __syncthreads();

    {
        f32x4 acc[2] = {{0.f, 0.f, 0.f, 0.f}, {0.f, 0.f, 0.f, 0.f}};
#pragma unroll
        for (int k = 0; k < 9; ++k) {
            const int kh = k / 3;
            const int kw = k - kh * 3;
            const int y = h + kh - 1;
            const int xx = w0 + (wid << 4) + ln15 + kw - 1;
            U4B8 a0, a1;
            a0.u = make_uint4(0u, 0u, 0u, 0u);
            a1.u = make_uint4(0u, 0u, 0u, 0u);
            if (y >= 0 && y < IH && xx >= 0 && xx < IW) {
                const unsigned short* p = xb + (((size_t)((y << 7) + xx)) << 6) + (quad << 3);
                a0.u = *(const uint4*)p;
                a1.u = *(const uint4*)(p + 32);
            }
            const unsigned short* wb  = wall + (((k << 3) + quad) << 8);
            const unsigned short* wb4 = wall + (((k << 3) + quad + 4) << 8);
#pragma unroll
            for (int ot = 0; ot < 2; ++ot) {
                U4B8 b0, b1;
                b0.u = *(const uint4*)&wb [((ot << 4) + ln15) << 3];
                b1.u = *(const uint4*)&wb4[((ot << 4) + ln15) << 3];
                acc[ot] = __builtin_amdgcn_mfma_f32_16x16x32_bf16(a0.h, b0.h, acc[ot], 0, 0, 0);
                acc[ot] = __builtin_amdgcn_mfma_f32_16x16x32_bf16(a1.h, b1.h, acc[ot], 0, 0, 0);
            }
        }
        // epilogue to LDS offs[o][68]: col(o)=ln15+16ot, row(px)=quad*4+reg
#pragma unroll
        for (int ot = 0; ot < 2; ++ot) {
            const int o = (ot << 4) + ln15;
            if (o < 27) {
                const float bias = b_om[o];
                float4 r;
                r.x = acc[ot][0] + bias;
                r.y = acc[ot][1] + bias;
                r.z = acc[ot][2] + bias;
                r.w = acc[ot][3] + bias;
                if (o >= 18) {
                    r.x = 2.0f / (1.0f + __expf(-r.x));
                    r.y = 2.0f / (1.0f + __expf(-r.y));
                    r.z = 2.0f / (1.0f + __expf(-r.z));
                    r.w = 2.0f / (1.0f + __expf(-r.w));
                }
                *(float4*)&offs[o * 68 + (wid << 4) + (quad << 2)] = r;
            }
        }
    }
    __syncthreads();   // offs complete + conv wall reads done

    // ---------------- phase 2: deformable conv ----------------
    // stage dc wall: 4608 uint4, layout [(k*8+p)*64 + o]
    for (int s = tid; s < 4608; s += 256) {
        const int k = s >> 9;
        const int r = s & 511;
        const int p = r >> 6;
        const int o = r & 63;
        ((uint4*)wall)[s] = ((const uint4*)wt_dc16)[(k << 9) + (o << 3) + p];
    }
    __syncthreads();

    const int lpx = (wid << 4) + ln15;   // local pixel this lane gathers/owns

    f32x4 acc[4];
#pragma unroll
    for (int i = 0; i < 4; ++i) acc[i] = (f32x4){0.f, 0.f, 0.f, 0.f};

#pragma unroll
    for (int k = 0; k < 9; ++k) {
        const float offy = offs[(2 * k) * 68 + lpx];
        const float offx = offs[(2 * k + 1) * 68 + lpx];
        const float msk  = offs[(18 + k) * 68 + lpx];
        const int kh = k / 3;
        const int kw = k - kh * 3;
        const float py  = (float)(h + kh - 1) + offy;
        const float pxf = (float)(w0 + lpx + kw - 1) + offx;
        const float y0f = floorf(py);
        const float x0f = floorf(pxf);
        const float fy = py - y0f;
        const float fx = pxf - x0f;
        const float wy0 = 1.0f - fy, wx0 = 1.0f - fx;
        const float vy0 = (y0f >= 0.0f && y0f <= 127.0f) ? 1.0f : 0.0f;
        const float vy1 = (y0f >= -1.0f && y0f <= 126.0f) ? 1.0f : 0.0f;
        const float vx0 = (x0f >= 0.0f && x0f <= 127.0f) ? 1.0f : 0.0f;
        const float vx1 = (x0f >= -1.0f && x0f <= 126.0f) ? 1.0f : 0.0f;
        const float w00 = wy0 * wx0 * vy0 * vx0;
        const float w01 = wy0 * fx  * vy0 * vx1;
        const float w10 = fy  * wx0 * vy1 * vx0;
        const float w11 = fy  * fx  * vy1 * vx1;
        const int y0i = min(max((int)y0f, 0), 127);
        const int y1i = min(max((int)y0f + 1, 0), 127);
        const int x0i = min(max((int)x0f, 0), 127);
        const int x1i = min(max((int)x0f + 1, 0), 127);

        float v[16];
#pragma unroll
        for (int i = 0; i < 16; ++i) v[i] = 0.0f;
        const int cofs = quad << 3;
        corner2(xb + ((((size_t)((y0i << 7) + x0i)) << 6) + cofs), w00, v);
        corner2(xb + ((((size_t)((y0i << 7) + x1i)) << 6) + cofs), w01, v);
        corner2(xb + ((((size_t)((y1i << 7) + x0i)) << 6) + cofs), w10, v);
        corner2(xb + ((((size_t)((y1i << 7) + x1i)) << 6) + cofs), w11, v);

        U4B8 a0, a1;
        unsigned int pk[8];
#pragma unroll
        for (int i = 0; i < 8; ++i) {
            const unsigned int lo = f32_to_bf16(v[2 * i] * msk);
            const unsigned int hi = f32_to_bf16(v[2 * i + 1] * msk);
            pk[i] = lo | (hi << 16);
        }
        a0.u = make_uint4(pk[0], pk[1], pk[2], pk[3]);
        a1.u = make_uint4(pk[4], pk[5], pk[6], pk[7]);

        const unsigned short* wb  = wall + (((k << 3) + quad) << 9);
        const unsigned short* wb4 = wall + (((k << 3) + quad + 4) << 9);
#pragma unroll
        for (int ot = 0; ot < 4; ++ot) {
            U4B8 b0, b1;
            b0.u = *(const uint4*)&wb [((ot << 4) + ln15) << 3];
            b1.u = *(const uint4*)&wb4[((ot << 4) + ln15) << 3];
            acc[ot] = __builtin_amdgcn_mfma_f32_16x16x32_bf16(a0.h, b0.h, acc[ot], 0, 0, 0);
            acc[ot] = __builtin_amdgcn_mfma_f32_16x16x32_bf16(a1.h, b1.h, acc[ot], 0, 0, 0);
        }
    }

    // epilogue: col(o)=lane&15, row(px)=quad*4+reg
#pragma unroll
    for (int ot = 0; ot < 4; ++ot) {
        const int o = (ot << 4) + ln15;
        const float bias = b_dc[o];
        float4 r;
        r.x = acc[ot][0] + bias;
        r.y = acc[ot][1] + bias;
        r.z = acc[ot][2] + bias;
        r.w = acc[ot][3] + bias;
        *(float4*)&out[(((size_t)(b * 64 + o)) << 14) + (h << 7) + w0 + (wid << 4) + (quad << 2)] = r;
    }
}

extern "C" void kernel_launch(void* const* d_in, const int* in_sizes, int n_in,
                              void* d_out, int out_size, void* d_ws, size_t ws_size,
                              hipStream_t stream) {
    const float* x    = (const float*)d_in[0];
    const float* w_om = (const float*)d_in[1];
    const float* b_om = (const float*)d_in[2];
    const float* w_dc = (const float*)d_in[3];
    const float* b_dc = (const float*)d_in[4];
    float* out = (float*)d_out;
    float* ws  = (float*)d_ws;

    unsigned short* xT      = (unsigned short*)(ws + XT_OFF);
    unsigned short* wt_dc16 = (unsigned short*)(ws + WTDC_OFF);
    unsigned short* wt_om16 = (unsigned short*)(ws + WTOM_OFF);

    // 64-px strips: NB*IH*(IW/64) = 2048 blocks
    const int n_blocks = NB * IH * (IW / 64);

    transpose_weights<<<144, 256, 0, stream>>>(w_dc, w_om, wt_dc16, wt_om16);
    transpose_x<<<NB * IH * 2, 256, 0, stream>>>(x, xT);
    fused_dcn<<<n_blocks, 256, 0, stream>>>(xT, b_om, wt_om16, b_dc, wt_dc16, out);
}